// Round 4
// baseline (5628.790 us; speedup 1.0000x reference)
//
#include <hip/hip_runtime.h>
#include <stdint.h>

#define N_PTS 262144
#define HID 100
#define KPAD 128
#define WSTRIDE 112

// ---- faithful fp32 fake-quant of a pre-activation ------------------------
// np: h = tanhf32(pre); q = clip(round(h/sx)); xq = q*sx  (all fp32 elementwise)
// Decision from correctly-rounded tanh (fp64 fallback near half-integer
// boundaries; fast-path error ~2.3e-5 << 1e-4 guard).
__device__ __forceinline__ float qmat(float pre, float sx) {
  const float hf = tanhf(pre);
  float r = hf / sx;                       // IEEE fp32 division, like np
  float rr = rintf(r);                     // round-half-even = np.round
  if (__builtin_expect(fabsf(r - rr) > 0.4999f, 0)) {
    const float hc = (float)tanh((double)pre);  // correctly-rounded fp32 tanh
    r = hc / sx;
    rr = rintf(r);
  }
  rr = fminf(fmaxf(rr, -127.0f), 127.0f);
  return rr * sx;                          // fp32 materialization, like np
}

// ---------------- input max: max(|z|,|t|) as float bits --------------------
__global__ __launch_bounds__(256) void inmax_kernel(const float* __restrict__ z,
                                                    const float* __restrict__ t,
                                                    int* __restrict__ inbits) {
  float m = 0.0f;
  const int stride = gridDim.x * blockDim.x;
  for (int i = blockIdx.x * blockDim.x + threadIdx.x; i < N_PTS; i += stride) {
    m = fmaxf(m, fabsf(z[i]));
    m = fmaxf(m, fabsf(t[i]));
  }
  __shared__ float red[256];
  red[threadIdx.x] = m;
  __syncthreads();
  for (int s = 128; s > 0; s >>= 1) {
    if (threadIdx.x < s) red[threadIdx.x] = fmaxf(red[threadIdx.x], red[threadIdx.x + s]);
    __syncthreads();
  }
  if (threadIdx.x == 0) atomicMax(inbits, __float_as_int(red[0]));  // non-neg bits
}

// ---------------- weight prep: sw + MATERIALIZED wq = fl32(qw*sw) ----------
// blocks 0..4: W2..W6 -> wq32[b][100][WSTRIDE]; 5: W1 -> w1c0/w1c1; 6: Wout -> wo0/wo1
__global__ __launch_bounds__(256) void prep_kernel(
    const float* __restrict__ W1, const float* __restrict__ W2, const float* __restrict__ W3,
    const float* __restrict__ W4, const float* __restrict__ W5, const float* __restrict__ W6,
    const float* __restrict__ Wout,
    float* __restrict__ wq32, float* __restrict__ w1c0, float* __restrict__ w1c1,
    float* __restrict__ wo0, float* __restrict__ wo1, float* __restrict__ swv) {
  const int b = blockIdx.x;
  const float* W;
  int n;
  if (b < 5) { W = (b == 0) ? W2 : (b == 1) ? W3 : (b == 2) ? W4 : (b == 3) ? W5 : W6; n = HID * HID; }
  else if (b == 5) { W = W1; n = HID * 2; }
  else { W = Wout; n = 2 * HID; }

  float m = 0.0f;
  for (int i = threadIdx.x; i < n; i += 256) m = fmaxf(m, fabsf(W[i]));
  __shared__ float red[256];
  red[threadIdx.x] = m;
  __syncthreads();
  for (int s = 128; s > 0; s >>= 1) {
    if (threadIdx.x < s) red[threadIdx.x] = fmaxf(red[threadIdx.x], red[threadIdx.x + s]);
    __syncthreads();
  }
  const float sw = fmaxf(red[0] / 127.0f, 1e-12f);   // fp32 division, like np
  if (threadIdx.x == 0) {
    const int layer = (b < 5) ? (b + 2) : ((b == 5) ? 1 : 7);
    swv[layer] = sw;
  }
  if (b < 5) {
    float* dst = wq32 + (size_t)b * HID * WSTRIDE;
    for (int i = threadIdx.x; i < HID * WSTRIDE; i += 256) {
      const int r = i / WSTRIDE, k = i - r * WSTRIDE;
      float v = 0.0f;
      if (k < HID) {
        float q = rintf(W[r * HID + k] / sw);
        q = fminf(fmaxf(q, -127.0f), 127.0f);
        v = q * sw;                                  // materialize fl32(qw*sw)
      }
      dst[i] = v;
    }
  } else if (b == 5) {
    for (int j = threadIdx.x; j < HID; j += 256) {
      float q0 = rintf(W[j * 2 + 0] / sw);
      q0 = fminf(fmaxf(q0, -127.0f), 127.0f);
      w1c0[j] = q0 * sw;
      float q1 = rintf(W[j * 2 + 1] / sw);
      q1 = fminf(fmaxf(q1, -127.0f), 127.0f);
      w1c1[j] = q1 * sw;
    }
  } else {
    for (int k = threadIdx.x; k < HID; k += 256) {
      float q0 = rintf(W[k] / sw);
      q0 = fminf(fmaxf(q0, -127.0f), 127.0f);
      wo0[k] = q0 * sw;
      float q1 = rintf(W[HID + k] / sw);
      q1 = fminf(fmaxf(q1, -127.0f), 127.0f);
      wo1[k] = q1 * sw;
    }
  }
}

// ---------------- scale chain: sx[stage] + materialized bias for stage+1 ---
__global__ void scale_kernel(int stage, const float* __restrict__ bnext, int nbn,
                             const float* __restrict__ swv, float* __restrict__ sxv,
                             float* __restrict__ bq32, const int* __restrict__ maxpre,
                             const int* __restrict__ inbits) {
  __shared__ float s_sb;
  if (threadIdx.x == 0) {
    float sx;
    if (stage == 0) {
      sx = __int_as_float(inbits[0]) / 127.0f;
    } else {
      // max|h| = fl32(tanh64(max|pre|)): correctly-rounded tanh is odd+monotone
      const float mp = __int_as_float(maxpre[stage]);
      sx = (float)tanh((double)mp) / 127.0f;          // fp32 division
    }
    sx = fmaxf(sx, 1e-12f);
    sxv[stage] = sx;
    s_sb = sx * swv[stage + 1];                        // np's fp32 sb = sx*sw
  }
  __syncthreads();
  const float sb = s_sb;
  for (int j = threadIdx.x; j < KPAD; j += blockDim.x) {
    float v = 0.0f;
    if (j < nbn) {
      float q = rintf(bnext[j] / sb);                  // fp32 division
      q = fminf(fmaxf(q, -128.0f), 127.0f);            // Int8Bias clip
      v = q * sb;                                      // materialize fl32(q*sb)
    }
    bq32[(stage + 1) * KPAD + j] = v;
  }
}

// ---------------- layer 1: (z,t) -> pre1[N][100] (fp32) --------------------
__global__ __launch_bounds__(256) void layer1_kernel(
    const float* __restrict__ z, const float* __restrict__ t,
    const float* __restrict__ w1c0, const float* __restrict__ w1c1,
    const float* __restrict__ bq32, const float* __restrict__ sxv,
    float* __restrict__ buf, int* __restrict__ maxpre) {
  const float sx0 = sxv[0];
  const int row = blockIdx.x * 256 + threadIdx.x;
  float qz = rintf(z[row] / sx0);
  qz = fminf(fmaxf(qz, -127.0f), 127.0f);
  const float xz = qz * sx0;                           // materialized xq
  float qt = rintf(t[row] / sx0);
  qt = fminf(fmaxf(qt, -127.0f), 127.0f);
  const float xt = qt * sx0;

  float m = 0.0f;
  float* out = buf + (size_t)row * HID;
  for (int j4 = 0; j4 < 25; ++j4) {
    float st[4];
#pragma unroll
    for (int e = 0; e < 4; ++e) {
      const int j = j4 * 4 + e;
      const float mm = fmaf(xt, w1c1[j], xz * w1c0[j]);
      const float pre = mm + bq32[KPAD + j];
      st[e] = pre;
      m = fmaxf(m, fabsf(pre));
    }
    float4 v; v.x = st[0]; v.y = st[1]; v.z = st[2]; v.w = st[3];
    *(float4*)(out + j4 * 4) = v;
  }
  __shared__ float red[256];
  red[threadIdx.x] = m;
  __syncthreads();
  for (int s = 128; s > 0; s >>= 1) {
    if (threadIdx.x < s) red[threadIdx.x] = fmaxf(red[threadIdx.x], red[threadIdx.x + s]);
    __syncthreads();
  }
  if (threadIdx.x == 0) atomicMax(maxpre, __float_as_int(red[0]));
}

// ---------------- layers 2..6: in-place pre -> pre' ------------------------
// lane-per-row; weights read wave-uniform (scalar path); 4-way split-FMA sum.
__global__ __launch_bounds__(256) void layer_mid_kernel(
    float* buf, const float* __restrict__ wq, const float* __restrict__ bq,
    const float* __restrict__ sxp, int* __restrict__ maxpre) {
  const float sx = sxp[0];
  const int row = blockIdx.x * 256 + threadIdx.x;
  float* rp = buf + (size_t)row * HID;

  float xq[HID];
#pragma unroll
  for (int k4 = 0; k4 < 25; ++k4) {
    const float4 v = *(const float4*)(rp + k4 * 4);
    xq[k4 * 4 + 0] = v.x; xq[k4 * 4 + 1] = v.y;
    xq[k4 * 4 + 2] = v.z; xq[k4 * 4 + 3] = v.w;
  }
#pragma unroll
  for (int k = 0; k < HID; ++k) xq[k] = qmat(xq[k], sx);   // quant+materialize

  float m = 0.0f;
  for (int j4 = 0; j4 < 25; ++j4) {
    float st[4];
#pragma unroll
    for (int e = 0; e < 4; ++e) {
      const int j = j4 * 4 + e;
      const float* wr = wq + j * WSTRIDE;                  // wave-uniform
      float a0 = 0.0f, a1 = 0.0f, a2 = 0.0f, a3 = 0.0f;
#pragma unroll
      for (int k = 0; k < HID; k += 4) {
        a0 = fmaf(xq[k + 0], wr[k + 0], a0);
        a1 = fmaf(xq[k + 1], wr[k + 1], a1);
        a2 = fmaf(xq[k + 2], wr[k + 2], a2);
        a3 = fmaf(xq[k + 3], wr[k + 3], a3);
      }
      const float s = (a0 + a1) + (a2 + a3);
      const float pre = s + bq[j];
      st[e] = pre;
      m = fmaxf(m, fabsf(pre));
    }
    float4 v; v.x = st[0]; v.y = st[1]; v.z = st[2]; v.w = st[3];
    *(float4*)(rp + j4 * 4) = v;                           // safe: row fully read
  }
  __shared__ float red[256];
  red[threadIdx.x] = m;
  __syncthreads();
  for (int s = 128; s > 0; s >>= 1) {
    if (threadIdx.x < s) red[threadIdx.x] = fmaxf(red[threadIdx.x], red[threadIdx.x + s]);
    __syncthreads();
  }
  if (threadIdx.x == 0) atomicMax(maxpre, __float_as_int(red[0]));
}

// ---------------- output layer: pre6 -> out[N][2] --------------------------
__global__ __launch_bounds__(256) void layer_out_kernel(
    const float* __restrict__ buf, const float* __restrict__ wo0, const float* __restrict__ wo1,
    const float* __restrict__ bq32, const float* __restrict__ sxp,
    float* __restrict__ out) {
  const float sx = sxp[0];
  const int row = blockIdx.x * 256 + threadIdx.x;
  const float* rp = buf + (size_t)row * HID;
  float a00 = 0.0f, a01 = 0.0f, a02 = 0.0f, a03 = 0.0f;
  float a10 = 0.0f, a11 = 0.0f, a12 = 0.0f, a13 = 0.0f;
#pragma unroll
  for (int k4 = 0; k4 < 25; ++k4) {
    const float4 v = *(const float4*)(rp + k4 * 4);
    const float x0 = qmat(v.x, sx);
    const float x1 = qmat(v.y, sx);
    const float x2 = qmat(v.z, sx);
    const float x3 = qmat(v.w, sx);
    const int k = k4 * 4;
    a00 = fmaf(x0, wo0[k + 0], a00); a10 = fmaf(x0, wo1[k + 0], a10);
    a01 = fmaf(x1, wo0[k + 1], a01); a11 = fmaf(x1, wo1[k + 1], a11);
    a02 = fmaf(x2, wo0[k + 2], a02); a12 = fmaf(x2, wo1[k + 2], a12);
    a03 = fmaf(x3, wo0[k + 3], a03); a13 = fmaf(x3, wo1[k + 3], a13);
  }
  float2 o;
  o.x = ((a00 + a01) + (a02 + a03)) + bq32[7 * KPAD + 0];
  o.y = ((a10 + a11) + (a12 + a13)) + bq32[7 * KPAD + 1];
  *(float2*)(out + (size_t)row * 2) = o;
}

extern "C" void kernel_launch(void* const* d_in, const int* in_sizes, int n_in,
                              void* d_out, int out_size, void* d_ws, size_t ws_size,
                              hipStream_t stream) {
  const float* z = (const float*)d_in[0];
  const float* t = (const float*)d_in[1];
  const float* Wp[8];
  const float* Bp[8];
  for (int l = 1; l <= 7; ++l) {
    Wp[l] = (const float*)d_in[2 * l];
    Bp[l] = (const float*)d_in[2 * l + 1];
  }

  char* ws = (char*)d_ws;
  size_t off = 0;
  float* buf = (float*)(ws + off);    off += (size_t)N_PTS * HID * sizeof(float);      // 105 MB
  float* wq32 = (float*)(ws + off);   off += (size_t)5 * HID * WSTRIDE * sizeof(float); // 224 KB
  float* w1c0 = (float*)(ws + off);   off += 128 * sizeof(float);
  float* w1c1 = (float*)(ws + off);   off += 128 * sizeof(float);
  float* wo0 = (float*)(ws + off);    off += 128 * sizeof(float);
  float* wo1 = (float*)(ws + off);    off += 128 * sizeof(float);
  float* bq32 = (float*)(ws + off);   off += 8 * KPAD * sizeof(float);
  float* swv = (float*)(ws + off);    off += 16 * sizeof(float);
  float* sxv = (float*)(ws + off);    off += 16 * sizeof(float);
  int* maxpre = (int*)(ws + off);     off += 16 * sizeof(int);   // 0xAA poison negative: atomicMax-safe
  int* inbits = (int*)(ws + off);     off += 16 * sizeof(int);
  (void)ws_size; (void)in_sizes; (void)n_in; (void)out_size;

  inmax_kernel<<<512, 256, 0, stream>>>(z, t, inbits);
  prep_kernel<<<7, 256, 0, stream>>>(Wp[1], Wp[2], Wp[3], Wp[4], Wp[5], Wp[6], Wp[7],
                                     wq32, w1c0, w1c1, wo0, wo1, swv);
  scale_kernel<<<1, 128, 0, stream>>>(0, Bp[1], HID, swv, sxv, bq32, maxpre, inbits);
  layer1_kernel<<<N_PTS / 256, 256, 0, stream>>>(z, t, w1c0, w1c1, bq32, sxv, buf, maxpre + 1);
  for (int l = 2; l <= 6; ++l) {
    scale_kernel<<<1, 128, 0, stream>>>(l - 1, Bp[l], HID, swv, sxv, bq32, maxpre, inbits);
    layer_mid_kernel<<<N_PTS / 256, 256, 0, stream>>>(buf, wq32 + (size_t)(l - 2) * HID * WSTRIDE,
                                                      bq32 + l * KPAD, sxv + (l - 1), maxpre + l);
  }
  scale_kernel<<<1, 128, 0, stream>>>(6, Bp[7], 2, swv, sxv, bq32, maxpre, inbits);
  layer_out_kernel<<<N_PTS / 256, 256, 0, stream>>>(buf, wo0, wo1, bq32, sxv + 6, (float*)d_out);
}

// Round 5
// 1592.360 us; speedup vs baseline: 3.5349x; 3.5349x over previous
//
#include <hip/hip_runtime.h>
#include <stdint.h>

#define N_PTS 262144
#define HID 100
#define KPAD 128
#define WSTRIDE 112

// k-major tiled activation layout: element k of row r lives at
//   buf[(r>>6)*(HID*64) + k*64 + (r&63)]
// -> every per-lane access at fixed k is a 256B coalesced wave transaction.
__device__ __forceinline__ size_t buf_base(int row) {
  return (size_t)(row >> 6) * (HID * 64) + (row & 63);
}

// ---- faithful fp32 fake-quant of a pre-activation ------------------------
// np: h = tanhf32(pre); q = clip(round(h/sx)); xq = q*sx  (all fp32 elementwise)
// Decision from correctly-rounded tanh (fp64 fallback near half-integer
// boundaries; fast-path error ~2.3e-5 << 1e-4 guard).
__device__ __forceinline__ float qmat(float pre, float sx) {
  const float hf = tanhf(pre);
  float r = hf / sx;                       // IEEE fp32 division, like np
  float rr = rintf(r);                     // round-half-even = np.round
  if (__builtin_expect(fabsf(r - rr) > 0.4999f, 0)) {
    const float hc = (float)tanh((double)pre);  // correctly-rounded fp32 tanh
    r = hc / sx;
    rr = rintf(r);
  }
  rr = fminf(fmaxf(rr, -127.0f), 127.0f);
  return rr * sx;                          // fp32 materialization, like np
}

// ---------------- input max: max(|z|,|t|) as float bits --------------------
__global__ __launch_bounds__(256) void inmax_kernel(const float* __restrict__ z,
                                                    const float* __restrict__ t,
                                                    int* __restrict__ inbits) {
  float m = 0.0f;
  const int stride = gridDim.x * blockDim.x;
  for (int i = blockIdx.x * blockDim.x + threadIdx.x; i < N_PTS; i += stride) {
    m = fmaxf(m, fabsf(z[i]));
    m = fmaxf(m, fabsf(t[i]));
  }
  __shared__ float red[256];
  red[threadIdx.x] = m;
  __syncthreads();
  for (int s = 128; s > 0; s >>= 1) {
    if (threadIdx.x < s) red[threadIdx.x] = fmaxf(red[threadIdx.x], red[threadIdx.x + s]);
    __syncthreads();
  }
  if (threadIdx.x == 0) atomicMax(inbits, __float_as_int(red[0]));  // non-neg bits
}

// ---------------- weight prep: sw + MATERIALIZED wq = fl32(qw*sw) ----------
// blocks 0..4: W2..W6 -> wq32[b][100][WSTRIDE]; 5: W1 -> w1c0/w1c1; 6: Wout -> wo0/wo1
__global__ __launch_bounds__(256) void prep_kernel(
    const float* __restrict__ W1, const float* __restrict__ W2, const float* __restrict__ W3,
    const float* __restrict__ W4, const float* __restrict__ W5, const float* __restrict__ W6,
    const float* __restrict__ Wout,
    float* __restrict__ wq32, float* __restrict__ w1c0, float* __restrict__ w1c1,
    float* __restrict__ wo0, float* __restrict__ wo1, float* __restrict__ swv) {
  const int b = blockIdx.x;
  const float* W;
  int n;
  if (b < 5) { W = (b == 0) ? W2 : (b == 1) ? W3 : (b == 2) ? W4 : (b == 3) ? W5 : W6; n = HID * HID; }
  else if (b == 5) { W = W1; n = HID * 2; }
  else { W = Wout; n = 2 * HID; }

  float m = 0.0f;
  for (int i = threadIdx.x; i < n; i += 256) m = fmaxf(m, fabsf(W[i]));
  __shared__ float red[256];
  red[threadIdx.x] = m;
  __syncthreads();
  for (int s = 128; s > 0; s >>= 1) {
    if (threadIdx.x < s) red[threadIdx.x] = fmaxf(red[threadIdx.x], red[threadIdx.x + s]);
    __syncthreads();
  }
  const float sw = fmaxf(red[0] / 127.0f, 1e-12f);   // fp32 division, like np
  if (threadIdx.x == 0) {
    const int layer = (b < 5) ? (b + 2) : ((b == 5) ? 1 : 7);
    swv[layer] = sw;
  }
  if (b < 5) {
    float* dst = wq32 + (size_t)b * HID * WSTRIDE;
    for (int i = threadIdx.x; i < HID * WSTRIDE; i += 256) {
      const int r = i / WSTRIDE, k = i - r * WSTRIDE;
      float v = 0.0f;
      if (k < HID) {
        float q = rintf(W[r * HID + k] / sw);
        q = fminf(fmaxf(q, -127.0f), 127.0f);
        v = q * sw;                                  // materialize fl32(qw*sw)
      }
      dst[i] = v;
    }
  } else if (b == 5) {
    for (int j = threadIdx.x; j < HID; j += 256) {
      float q0 = rintf(W[j * 2 + 0] / sw);
      q0 = fminf(fmaxf(q0, -127.0f), 127.0f);
      w1c0[j] = q0 * sw;
      float q1 = rintf(W[j * 2 + 1] / sw);
      q1 = fminf(fmaxf(q1, -127.0f), 127.0f);
      w1c1[j] = q1 * sw;
    }
  } else {
    for (int k = threadIdx.x; k < HID; k += 256) {
      float q0 = rintf(W[k] / sw);
      q0 = fminf(fmaxf(q0, -127.0f), 127.0f);
      wo0[k] = q0 * sw;
      float q1 = rintf(W[HID + k] / sw);
      q1 = fminf(fmaxf(q1, -127.0f), 127.0f);
      wo1[k] = q1 * sw;
    }
  }
}

// ---------------- scale chain: sx[stage] + materialized bias for stage+1 ---
__global__ void scale_kernel(int stage, const float* __restrict__ bnext, int nbn,
                             const float* __restrict__ swv, float* __restrict__ sxv,
                             float* __restrict__ bq32, const int* __restrict__ maxpre,
                             const int* __restrict__ inbits) {
  __shared__ float s_sb;
  if (threadIdx.x == 0) {
    float sx;
    if (stage == 0) {
      sx = __int_as_float(inbits[0]) / 127.0f;
    } else {
      // max|h| = fl32(tanh64(max|pre|)): correctly-rounded tanh is odd+monotone
      const float mp = __int_as_float(maxpre[stage]);
      sx = (float)tanh((double)mp) / 127.0f;          // fp32 division
    }
    sx = fmaxf(sx, 1e-12f);
    sxv[stage] = sx;
    s_sb = sx * swv[stage + 1];                        // np's fp32 sb = sx*sw
  }
  __syncthreads();
  const float sb = s_sb;
  for (int j = threadIdx.x; j < KPAD; j += blockDim.x) {
    float v = 0.0f;
    if (j < nbn) {
      float q = rintf(bnext[j] / sb);                  // fp32 division
      q = fminf(fmaxf(q, -128.0f), 127.0f);            // Int8Bias clip
      v = q * sb;                                      // materialize fl32(q*sb)
    }
    bq32[(stage + 1) * KPAD + j] = v;
  }
}

// ---------------- layer 1: (z,t) -> pre1 (k-major tiled) -------------------
__global__ __launch_bounds__(256) void layer1_kernel(
    const float* __restrict__ z, const float* __restrict__ t,
    const float* __restrict__ w1c0, const float* __restrict__ w1c1,
    const float* __restrict__ bq32, const float* __restrict__ sxv,
    float* __restrict__ buf, int* __restrict__ maxpre) {
  const float sx0 = sxv[0];
  const int row = blockIdx.x * 256 + threadIdx.x;
  float qz = rintf(z[row] / sx0);
  qz = fminf(fmaxf(qz, -127.0f), 127.0f);
  const float xz = qz * sx0;                           // materialized xq
  float qt = rintf(t[row] / sx0);
  qt = fminf(fmaxf(qt, -127.0f), 127.0f);
  const float xt = qt * sx0;

  float m = 0.0f;
  float* out = buf + buf_base(row);
#pragma unroll 4
  for (int j = 0; j < HID; ++j) {
    const float mm = fmaf(xt, w1c1[j], xz * w1c0[j]);
    const float pre = mm + bq32[KPAD + j];
    out[j * 64] = pre;                                 // coalesced: lane-contig
    m = fmaxf(m, fabsf(pre));
  }
  __shared__ float red[256];
  red[threadIdx.x] = m;
  __syncthreads();
  for (int s = 128; s > 0; s >>= 1) {
    if (threadIdx.x < s) red[threadIdx.x] = fmaxf(red[threadIdx.x], red[threadIdx.x + s]);
    __syncthreads();
  }
  if (threadIdx.x == 0) atomicMax(maxpre, __float_as_int(red[0]));
}

// ---------------- layers 2..6: in-place pre -> pre' (k-major tiled) --------
// lane-per-row; weights read wave-uniform (scalar path); 4-way split-FMA sum.
// Arithmetic identical to round-4 (same qmat decisions, same k-order) —
// only the global-memory layout changed.
__global__ __launch_bounds__(256) void layer_mid_kernel(
    float* buf, const float* __restrict__ wq, const float* __restrict__ bq,
    const float* __restrict__ sxp, int* __restrict__ maxpre) {
  const float sx = sxp[0];
  const int row = blockIdx.x * 256 + threadIdx.x;
  float* rp = buf + buf_base(row);

  float xq[HID];
#pragma unroll
  for (int k = 0; k < HID; ++k) xq[k] = rp[k * 64];        // coalesced loads
#pragma unroll
  for (int k = 0; k < HID; ++k) xq[k] = qmat(xq[k], sx);   // quant+materialize

  float m = 0.0f;
  for (int j4 = 0; j4 < 25; ++j4) {
    float st[4];
#pragma unroll
    for (int e = 0; e < 4; ++e) {
      const int j = j4 * 4 + e;
      const float* wr = wq + j * WSTRIDE;                  // wave-uniform
      float a0 = 0.0f, a1 = 0.0f, a2 = 0.0f, a3 = 0.0f;
#pragma unroll
      for (int k = 0; k < HID; k += 4) {
        a0 = fmaf(xq[k + 0], wr[k + 0], a0);
        a1 = fmaf(xq[k + 1], wr[k + 1], a1);
        a2 = fmaf(xq[k + 2], wr[k + 2], a2);
        a3 = fmaf(xq[k + 3], wr[k + 3], a3);
      }
      const float s = (a0 + a1) + (a2 + a3);
      const float pre = s + bq[j];
      st[e] = pre;
      m = fmaxf(m, fabsf(pre));
    }
#pragma unroll
    for (int e = 0; e < 4; ++e) rp[(j4 * 4 + e) * 64] = st[e];  // coalesced
  }
  __shared__ float red[256];
  red[threadIdx.x] = m;
  __syncthreads();
  for (int s = 128; s > 0; s >>= 1) {
    if (threadIdx.x < s) red[threadIdx.x] = fmaxf(red[threadIdx.x], red[threadIdx.x + s]);
    __syncthreads();
  }
  if (threadIdx.x == 0) atomicMax(maxpre, __float_as_int(red[0]));
}

// ---------------- output layer: pre6 -> out[N][2] --------------------------
__global__ __launch_bounds__(256) void layer_out_kernel(
    const float* __restrict__ buf, const float* __restrict__ wo0, const float* __restrict__ wo1,
    const float* __restrict__ bq32, const float* __restrict__ sxp,
    float* __restrict__ out) {
  const float sx = sxp[0];
  const int row = blockIdx.x * 256 + threadIdx.x;
  const float* rp = buf + buf_base(row);
  float a00 = 0.0f, a01 = 0.0f, a02 = 0.0f, a03 = 0.0f;
  float a10 = 0.0f, a11 = 0.0f, a12 = 0.0f, a13 = 0.0f;
#pragma unroll
  for (int k4 = 0; k4 < 25; ++k4) {
    const int k = k4 * 4;
    const float x0 = qmat(rp[(k + 0) * 64], sx);
    const float x1 = qmat(rp[(k + 1) * 64], sx);
    const float x2 = qmat(rp[(k + 2) * 64], sx);
    const float x3 = qmat(rp[(k + 3) * 64], sx);
    a00 = fmaf(x0, wo0[k + 0], a00); a10 = fmaf(x0, wo1[k + 0], a10);
    a01 = fmaf(x1, wo0[k + 1], a01); a11 = fmaf(x1, wo1[k + 1], a11);
    a02 = fmaf(x2, wo0[k + 2], a02); a12 = fmaf(x2, wo1[k + 2], a12);
    a03 = fmaf(x3, wo0[k + 3], a03); a13 = fmaf(x3, wo1[k + 3], a13);
  }
  float2 o;
  o.x = ((a00 + a01) + (a02 + a03)) + bq32[7 * KPAD + 0];
  o.y = ((a10 + a11) + (a12 + a13)) + bq32[7 * KPAD + 1];
  *(float2*)(out + (size_t)row * 2) = o;
}

extern "C" void kernel_launch(void* const* d_in, const int* in_sizes, int n_in,
                              void* d_out, int out_size, void* d_ws, size_t ws_size,
                              hipStream_t stream) {
  const float* z = (const float*)d_in[0];
  const float* t = (const float*)d_in[1];
  const float* Wp[8];
  const float* Bp[8];
  for (int l = 1; l <= 7; ++l) {
    Wp[l] = (const float*)d_in[2 * l];
    Bp[l] = (const float*)d_in[2 * l + 1];
  }

  char* ws = (char*)d_ws;
  size_t off = 0;
  float* buf = (float*)(ws + off);    off += (size_t)N_PTS * HID * sizeof(float);      // 105 MB
  float* wq32 = (float*)(ws + off);   off += (size_t)5 * HID * WSTRIDE * sizeof(float); // 224 KB
  float* w1c0 = (float*)(ws + off);   off += 128 * sizeof(float);
  float* w1c1 = (float*)(ws + off);   off += 128 * sizeof(float);
  float* wo0 = (float*)(ws + off);    off += 128 * sizeof(float);
  float* wo1 = (float*)(ws + off);    off += 128 * sizeof(float);
  float* bq32 = (float*)(ws + off);   off += 8 * KPAD * sizeof(float);
  float* swv = (float*)(ws + off);    off += 16 * sizeof(float);
  float* sxv = (float*)(ws + off);    off += 16 * sizeof(float);
  int* maxpre = (int*)(ws + off);     off += 16 * sizeof(int);   // 0xAA poison negative: atomicMax-safe
  int* inbits = (int*)(ws + off);     off += 16 * sizeof(int);
  (void)ws_size; (void)in_sizes; (void)n_in; (void)out_size;

  inmax_kernel<<<512, 256, 0, stream>>>(z, t, inbits);
  prep_kernel<<<7, 256, 0, stream>>>(Wp[1], Wp[2], Wp[3], Wp[4], Wp[5], Wp[6], Wp[7],
                                     wq32, w1c0, w1c1, wo0, wo1, swv);
  scale_kernel<<<1, 128, 0, stream>>>(0, Bp[1], HID, swv, sxv, bq32, maxpre, inbits);
  layer1_kernel<<<N_PTS / 256, 256, 0, stream>>>(z, t, w1c0, w1c1, bq32, sxv, buf, maxpre + 1);
  for (int l = 2; l <= 6; ++l) {
    scale_kernel<<<1, 128, 0, stream>>>(l - 1, Bp[l], HID, swv, sxv, bq32, maxpre, inbits);
    layer_mid_kernel<<<N_PTS / 256, 256, 0, stream>>>(buf, wq32 + (size_t)(l - 2) * HID * WSTRIDE,
                                                      bq32 + l * KPAD, sxv + (l - 1), maxpre + l);
  }
  scale_kernel<<<1, 128, 0, stream>>>(6, Bp[7], 2, swv, sxv, bq32, maxpre, inbits);
  layer_out_kernel<<<N_PTS / 256, 256, 0, stream>>>(buf, wo0, wo1, bq32, sxv + 6, (float*)d_out);
}

// Round 6
// 1444.657 us; speedup vs baseline: 3.8963x; 1.1022x over previous
//
#include <hip/hip_runtime.h>
#include <stdint.h>

#define N_PTS 262144
#define HID 100
#define KPAD 128
#define WSTRIDE 112
#define GUARD 0.498f

// k-major tiled activation layout: element k of row r lives at
//   buf[(r>>6)*(HID*64) + k*64 + (r&63)]
__device__ __forceinline__ size_t buf_base(int row) {
  return (size_t)(row >> 6) * (HID * 64) + (row & 63);
}

// Fast tanh: 1 - 2/(exp2(2*log2e*x)+1). v_exp_f32 (1ulp) + rcp + 1 Newton.
// Abs error in r-units (r = h/sx, |r|<=127) <= ~2.5e-4 << GUARD band 2e-3.
__device__ __forceinline__ float fast_tanh(float x) {
  float y = x * 2.885390081777927f;            // 2*log2(e)
  y = fminf(y, 126.0f);                        // avoid inf -> NaN in NR
  const float t = __builtin_amdgcn_exp2f(y);
  const float d = t + 1.0f;
  float r0 = __builtin_amdgcn_rcpf(d);
  r0 = fmaf(fmaf(-d, r0, 1.0f), r0, r0);       // Newton: ~1ulp reciprocal
  return fmaf(-2.0f, r0, 1.0f);
}

// Exact decision (cold path): h = fl32(tanh64(pre)); q = clip(rint(h/sx));
// returns materialized q*sx. Bitwise matches rounds 4/5 semantics.
__device__ __noinline__ float qslow(float pre, float sx) {
  const float h = (float)tanh((double)pre);
  float rr = rintf(h / sx);                    // IEEE fp32 division, like np
  rr = fminf(fmaxf(rr, -127.0f), 127.0f);
  return rr * sx;
}

// Branchy fast+exact quant (used where no register-array pressure exists).
__device__ __forceinline__ float qmat(float pre, float sx, float isx) {
  const float h = fast_tanh(pre);
  const float r = h * isx;
  const float rr = rintf(r);
  if (__builtin_expect(fabsf(r - rr) > GUARD, 0)) return qslow(pre, sx);
  const float rc = fminf(fmaxf(rr, -127.0f), 127.0f);
  return rc * sx;
}

#define FOR25(M) M(0) M(1) M(2) M(3) M(4) M(5) M(6) M(7) M(8) M(9) M(10) \
  M(11) M(12) M(13) M(14) M(15) M(16) M(17) M(18) M(19) M(20) M(21) M(22) M(23) M(24)

// ---------------- input max ------------------------------------------------
__global__ __launch_bounds__(256) void inmax_kernel(const float* __restrict__ z,
                                                    const float* __restrict__ t,
                                                    int* __restrict__ inbits) {
  float m = 0.0f;
  const int stride = gridDim.x * blockDim.x;
  for (int i = blockIdx.x * blockDim.x + threadIdx.x; i < N_PTS; i += stride) {
    m = fmaxf(m, fabsf(z[i]));
    m = fmaxf(m, fabsf(t[i]));
  }
  __shared__ float red[256];
  red[threadIdx.x] = m;
  __syncthreads();
  for (int s = 128; s > 0; s >>= 1) {
    if (threadIdx.x < s) red[threadIdx.x] = fmaxf(red[threadIdx.x], red[threadIdx.x + s]);
    __syncthreads();
  }
  if (threadIdx.x == 0) atomicMax(inbits, __float_as_int(red[0]));  // non-neg bits
}

// ---------------- weight prep ----------------------------------------------
__global__ __launch_bounds__(256) void prep_kernel(
    const float* __restrict__ W1, const float* __restrict__ W2, const float* __restrict__ W3,
    const float* __restrict__ W4, const float* __restrict__ W5, const float* __restrict__ W6,
    const float* __restrict__ Wout,
    float* __restrict__ wq32, float* __restrict__ w1c0, float* __restrict__ w1c1,
    float* __restrict__ wo0, float* __restrict__ wo1, float* __restrict__ swv) {
  const int b = blockIdx.x;
  const float* W;
  int n;
  if (b < 5) { W = (b == 0) ? W2 : (b == 1) ? W3 : (b == 2) ? W4 : (b == 3) ? W5 : W6; n = HID * HID; }
  else if (b == 5) { W = W1; n = HID * 2; }
  else { W = Wout; n = 2 * HID; }

  float m = 0.0f;
  for (int i = threadIdx.x; i < n; i += 256) m = fmaxf(m, fabsf(W[i]));
  __shared__ float red[256];
  red[threadIdx.x] = m;
  __syncthreads();
  for (int s = 128; s > 0; s >>= 1) {
    if (threadIdx.x < s) red[threadIdx.x] = fmaxf(red[threadIdx.x], red[threadIdx.x + s]);
    __syncthreads();
  }
  const float sw = fmaxf(red[0] / 127.0f, 1e-12f);
  if (threadIdx.x == 0) {
    const int layer = (b < 5) ? (b + 2) : ((b == 5) ? 1 : 7);
    swv[layer] = sw;
  }
  if (b < 5) {
    float* dst = wq32 + (size_t)b * HID * WSTRIDE;
    for (int i = threadIdx.x; i < HID * WSTRIDE; i += 256) {
      const int r = i / WSTRIDE, k = i - r * WSTRIDE;
      float v = 0.0f;
      if (k < HID) {
        float q = rintf(W[r * HID + k] / sw);
        q = fminf(fmaxf(q, -127.0f), 127.0f);
        v = q * sw;
      }
      dst[i] = v;
    }
  } else if (b == 5) {
    for (int j = threadIdx.x; j < HID; j += 256) {
      float q0 = rintf(W[j * 2 + 0] / sw);
      q0 = fminf(fmaxf(q0, -127.0f), 127.0f);
      w1c0[j] = q0 * sw;
      float q1 = rintf(W[j * 2 + 1] / sw);
      q1 = fminf(fmaxf(q1, -127.0f), 127.0f);
      w1c1[j] = q1 * sw;
    }
  } else {
    for (int k = threadIdx.x; k < HID; k += 256) {
      float q0 = rintf(W[k] / sw);
      q0 = fminf(fmaxf(q0, -127.0f), 127.0f);
      wo0[k] = q0 * sw;
      float q1 = rintf(W[HID + k] / sw);
      q1 = fminf(fmaxf(q1, -127.0f), 127.0f);
      wo1[k] = q1 * sw;
    }
  }
}

// ---------------- scale chain ----------------------------------------------
__global__ void scale_kernel(int stage, const float* __restrict__ bnext, int nbn,
                             const float* __restrict__ swv, float* __restrict__ sxv,
                             float* __restrict__ bq32, const int* __restrict__ maxpre,
                             const int* __restrict__ inbits) {
  __shared__ float s_sb;
  if (threadIdx.x == 0) {
    float sx;
    if (stage == 0) {
      sx = __int_as_float(inbits[0]) / 127.0f;
    } else {
      const float mp = __int_as_float(maxpre[stage]);
      sx = (float)tanh((double)mp) / 127.0f;   // fl32(tanh64(maxpre)), fp32 div
    }
    sx = fmaxf(sx, 1e-12f);
    sxv[stage] = sx;
    s_sb = sx * swv[stage + 1];
  }
  __syncthreads();
  const float sb = s_sb;
  for (int j = threadIdx.x; j < KPAD; j += blockDim.x) {
    float v = 0.0f;
    if (j < nbn) {
      float q = rintf(bnext[j] / sb);
      q = fminf(fmaxf(q, -128.0f), 127.0f);    // Int8Bias clip
      v = q * sb;
    }
    bq32[(stage + 1) * KPAD + j] = v;
  }
}

// ---------------- layer 1 --------------------------------------------------
__global__ __launch_bounds__(256) void layer1_kernel(
    const float* __restrict__ z, const float* __restrict__ t,
    const float* __restrict__ w1c0, const float* __restrict__ w1c1,
    const float* __restrict__ bq32, const float* __restrict__ sxv,
    float* __restrict__ buf, int* __restrict__ maxpre) {
  const float sx0 = sxv[0];
  const int row = blockIdx.x * 256 + threadIdx.x;
  float qz = rintf(z[row] / sx0);
  qz = fminf(fmaxf(qz, -127.0f), 127.0f);
  const float xz = qz * sx0;
  float qt = rintf(t[row] / sx0);
  qt = fminf(fmaxf(qt, -127.0f), 127.0f);
  const float xt = qt * sx0;

  float m = 0.0f;
  float* out = buf + buf_base(row);
#pragma unroll 4
  for (int j = 0; j < HID; ++j) {
    const float mm = fmaf(xt, w1c1[j], xz * w1c0[j]);
    const float pre = mm + bq32[KPAD + j];
    out[j * 64] = pre;
    m = fmaxf(m, fabsf(pre));
  }
  __shared__ float red[256];
  red[threadIdx.x] = m;
  __syncthreads();
  for (int s = 128; s > 0; s >>= 1) {
    if (threadIdx.x < s) red[threadIdx.x] = fmaxf(red[threadIdx.x], red[threadIdx.x + s]);
    __syncthreads();
  }
  if (threadIdx.x == 0) atomicMax(maxpre, __float_as_int(red[0]));
}

// ---------------- layers 2..6: all xq in NAMED registers -------------------
// 25 float4 regs (x0..x24) hold the row; quant is straight-line fast-path with
// a 100-bit suspect mask; rare exact fp64 fixup patches regs via switch.
// Decisions == fl32(tanh64) everywhere == rounds 4/5 (bitwise-same output).
__global__ __launch_bounds__(256) void layer_mid_kernel(
    float* buf, const float* __restrict__ wq, const float* __restrict__ bq,
    const float* __restrict__ sxp, int* __restrict__ maxpre) {
  const float sx = sxp[0];
  const float isx = 1.0f / sx;
  const int row = blockIdx.x * 256 + threadIdx.x;
  float* rp = buf + buf_base(row);

#define DECL4(i) float4 x##i;
  FOR25(DECL4)
#undef DECL4
#define LOAD4(i)                 \
  x##i.x = rp[(4 * i + 0) * 64]; \
  x##i.y = rp[(4 * i + 1) * 64]; \
  x##i.z = rp[(4 * i + 2) * 64]; \
  x##i.w = rp[(4 * i + 3) * 64];
  FOR25(LOAD4)
#undef LOAD4

  unsigned long long m0 = 0ull, m1 = 0ull;
#define QE(i, comp, kk) {                                              \
    const float h_ = fast_tanh(x##i.comp);                             \
    const float r_ = h_ * isx;                                         \
    float rr_ = rintf(r_);                                             \
    const unsigned long long s_ = (fabsf(r_ - rr_) > GUARD) ? 1ull : 0ull; \
    if ((kk) < 64) m0 |= s_ << (kk); else m1 |= s_ << ((kk) - 64);     \
    rr_ = fminf(fmaxf(rr_, -127.0f), 127.0f);                          \
    x##i.comp = rr_ * sx; }
#define Q4(i) QE(i, x, 4*i+0) QE(i, y, 4*i+1) QE(i, z, 4*i+2) QE(i, w, 4*i+3)
  FOR25(Q4)
#undef Q4
#undef QE

  if (__builtin_expect((m0 | m1) != 0ull, 0)) {
    while (m0 | m1) {
      int k;
      if (m0) { k = __builtin_ctzll(m0); m0 &= m0 - 1ull; }
      else    { k = 64 + __builtin_ctzll(m1); m1 &= m1 - 1ull; }
      const float pre = rp[k * 64];          // original pre still in memory
      const float v = qslow(pre, sx);        // exact fl32(tanh64) decision
      switch (k) {
#define CASE4(i)                          \
        case 4 * i + 0: x##i.x = v; break; \
        case 4 * i + 1: x##i.y = v; break; \
        case 4 * i + 2: x##i.z = v; break; \
        case 4 * i + 3: x##i.w = v; break;
        FOR25(CASE4)
#undef CASE4
      }
    }
  }

  float m = 0.0f;
#define FMA4(i)                            \
  a0 = fmaf(x##i.x, wr[4 * i + 0], a0);    \
  a1 = fmaf(x##i.y, wr[4 * i + 1], a1);    \
  a2 = fmaf(x##i.z, wr[4 * i + 2], a2);    \
  a3 = fmaf(x##i.w, wr[4 * i + 3], a3);
#define DOTJ(e, dst) {                                   \
    const float* wr = wq + (j4 * 4 + (e)) * WSTRIDE;     \
    float a0 = 0.0f, a1 = 0.0f, a2 = 0.0f, a3 = 0.0f;    \
    FOR25(FMA4)                                          \
    dst = ((a0 + a1) + (a2 + a3)) + bq[j4 * 4 + (e)]; }
  for (int j4 = 0; j4 < 25; ++j4) {
    float s0, s1, s2, s3;
    DOTJ(0, s0) DOTJ(1, s1) DOTJ(2, s2) DOTJ(3, s3)
    m = fmaxf(m, fabsf(s0)); m = fmaxf(m, fabsf(s1));
    m = fmaxf(m, fabsf(s2)); m = fmaxf(m, fabsf(s3));
    rp[(j4 * 4 + 0) * 64] = s0;
    rp[(j4 * 4 + 1) * 64] = s1;
    rp[(j4 * 4 + 2) * 64] = s2;
    rp[(j4 * 4 + 3) * 64] = s3;
  }
#undef DOTJ
#undef FMA4

  __shared__ float red[256];
  red[threadIdx.x] = m;
  __syncthreads();
  for (int s = 128; s > 0; s >>= 1) {
    if (threadIdx.x < s) red[threadIdx.x] = fmaxf(red[threadIdx.x], red[threadIdx.x + s]);
    __syncthreads();
  }
  if (threadIdx.x == 0) atomicMax(maxpre, __float_as_int(red[0]));
}

// ---------------- output layer ---------------------------------------------
__global__ __launch_bounds__(256) void layer_out_kernel(
    const float* __restrict__ buf, const float* __restrict__ wo0, const float* __restrict__ wo1,
    const float* __restrict__ bq32, const float* __restrict__ sxp,
    float* __restrict__ out) {
  const float sx = sxp[0];
  const float isx = 1.0f / sx;
  const int row = blockIdx.x * blockDim.x + threadIdx.x;
  const float* rp = buf + buf_base(row);
  float a00 = 0.0f, a01 = 0.0f, a02 = 0.0f, a03 = 0.0f;
  float a10 = 0.0f, a11 = 0.0f, a12 = 0.0f, a13 = 0.0f;
  for (int k4 = 0; k4 < 25; ++k4) {       // rolled: values consumed immediately
    const int k = k4 * 4;
    const float x0 = qmat(rp[(k + 0) * 64], sx, isx);
    const float x1 = qmat(rp[(k + 1) * 64], sx, isx);
    const float x2 = qmat(rp[(k + 2) * 64], sx, isx);
    const float x3 = qmat(rp[(k + 3) * 64], sx, isx);
    a00 = fmaf(x0, wo0[k + 0], a00); a10 = fmaf(x0, wo1[k + 0], a10);
    a01 = fmaf(x1, wo0[k + 1], a01); a11 = fmaf(x1, wo1[k + 1], a11);
    a02 = fmaf(x2, wo0[k + 2], a02); a12 = fmaf(x2, wo1[k + 2], a12);
    a03 = fmaf(x3, wo0[k + 3], a03); a13 = fmaf(x3, wo1[k + 3], a13);
  }
  float2 o;
  o.x = ((a00 + a01) + (a02 + a03)) + bq32[7 * KPAD + 0];
  o.y = ((a10 + a11) + (a12 + a13)) + bq32[7 * KPAD + 1];
  *(float2*)(out + (size_t)row * 2) = o;
}

extern "C" void kernel_launch(void* const* d_in, const int* in_sizes, int n_in,
                              void* d_out, int out_size, void* d_ws, size_t ws_size,
                              hipStream_t stream) {
  const float* z = (const float*)d_in[0];
  const float* t = (const float*)d_in[1];
  const float* Wp[8];
  const float* Bp[8];
  for (int l = 1; l <= 7; ++l) {
    Wp[l] = (const float*)d_in[2 * l];
    Bp[l] = (const float*)d_in[2 * l + 1];
  }

  char* ws = (char*)d_ws;
  size_t off = 0;
  float* buf = (float*)(ws + off);    off += (size_t)N_PTS * HID * sizeof(float);       // 105 MB
  float* wq32 = (float*)(ws + off);   off += (size_t)5 * HID * WSTRIDE * sizeof(float);  // 224 KB
  float* w1c0 = (float*)(ws + off);   off += 128 * sizeof(float);
  float* w1c1 = (float*)(ws + off);   off += 128 * sizeof(float);
  float* wo0 = (float*)(ws + off);    off += 128 * sizeof(float);
  float* wo1 = (float*)(ws + off);    off += 128 * sizeof(float);
  float* bq32 = (float*)(ws + off);   off += 8 * KPAD * sizeof(float);
  float* swv = (float*)(ws + off);    off += 16 * sizeof(float);
  float* sxv = (float*)(ws + off);    off += 16 * sizeof(float);
  int* maxpre = (int*)(ws + off);     off += 16 * sizeof(int);  // 0xAA poison negative: atomicMax-safe
  int* inbits = (int*)(ws + off);     off += 16 * sizeof(int);
  (void)ws_size; (void)in_sizes; (void)n_in; (void)out_size;

  inmax_kernel<<<512, 256, 0, stream>>>(z, t, inbits);
  prep_kernel<<<7, 256, 0, stream>>>(Wp[1], Wp[2], Wp[3], Wp[4], Wp[5], Wp[6], Wp[7],
                                     wq32, w1c0, w1c1, wo0, wo1, swv);
  scale_kernel<<<1, 128, 0, stream>>>(0, Bp[1], HID, swv, sxv, bq32, maxpre, inbits);
  layer1_kernel<<<N_PTS / 256, 256, 0, stream>>>(z, t, w1c0, w1c1, bq32, sxv, buf, maxpre + 1);
  for (int l = 2; l <= 6; ++l) {
    scale_kernel<<<1, 128, 0, stream>>>(l - 1, Bp[l], HID, swv, sxv, bq32, maxpre, inbits);
    layer_mid_kernel<<<N_PTS / 256, 256, 0, stream>>>(buf, wq32 + (size_t)(l - 2) * HID * WSTRIDE,
                                                      bq32 + l * KPAD, sxv + (l - 1), maxpre + l);
  }
  scale_kernel<<<1, 128, 0, stream>>>(6, Bp[7], 2, swv, sxv, bq32, maxpre, inbits);
  layer_out_kernel<<<N_PTS / 256, 256, 0, stream>>>(buf, wo0, wo1, bq32, sxv + 6, (float*)d_out);
}